// Round 3
// baseline (1141.662 us; speedup 1.0000x reference)
//
#include <hip/hip_runtime.h>
#include <cstdint>
#include <cstddef>
#include <math.h>

#define C_     512
#define N1_    8192
#define N2_    131072
#define NTOT   139265
#define E_     1000000
#define K1_    820
#define K2_    3280
#define M_     4101
#define NB2    256          // N2 / 512 histogram chunks
#define NBM    273          // ceil(NTOT / 512) histogram chunks
#define FLATP  209920       // K1_ * NB2
#define CHP    820          // FLATP / 256 scan chunks
#define FLATM  1119573      // M_ * NBM
#define CHM    4374         // ceil(FLATM / 256)
#define NCHS   256          // number of scan chunks (both P and M)

#define G_     240          // grid: < 256 CUs -> all blocks resident at 1 blk/CU
#define BLK_   512
#define FITB   210          // fit-role blocks ((bid&7)!=3): 240 - 30
#define ZB     30           // zero-role blocks
#define ZTOT   15360        // ZB*512
#define NG16   8704         // (N1_+N2_)/16 row-groups for fit
#define PADC   544          // padded LDS row stride (4 groups of 136 floats)

// d_out offsets (float elements), in reference return order
#define OFF_XPOOL   0ull
#define OFF_A       2099712ull
#define OFF_BATCH   18917913ull
#define OFF_CLUSTER 18922014ull
#define OFF_NNT     19061279ull
#define OFF_NTREE   19065380ull
#define OFF_FIT     19069481ull
#define OFF_NXY     19208746ull
#define OUT_TOTAL   19216948ull

// Discrete decisions emulate the reference's float32 arithmetic bit-exactly:
// numpy pairwise summation for dot products / norm, __f*_rn elementwise ops
// (no fma contraction), f32 keys, stable index tiebreaks. Bucket lists use a
// STABLE deterministic scatter (bit-identical output every call).
// FROZEN NUMERICS: per-row op sequence in fit, q-sequential f64 adds in
// pool — do not reorder. Fit LDS padding changes ADDRESSES only.
// ONE persistent kernel, REGULAR launch (coop launch aborts under graph
// capture — round-2 failure). Grid barrier = software sense barrier with
// agent-scope atomics + __threadfence(); G_=240 < 256 CUs and
// __launch_bounds__(512,2) guarantee full co-residency.

struct MegaArgs {
    const float* x; const int* ei; const int* tree; const float* xy;
    const float* w1; const float* w2;
    float* out;
    float* f1s; float* f2s; float* thrXYF;
    int* cluster1; int* clusterAll; int* parentsA; int* plist; int* clusterLst;
    int* bcP; int* bcM;
    int* totP; int* coffP; int* totM; int* coffM;
    int* rankArr; int* minTreeNeg;
    int* cand;
    int* barCnt; int* barGen;
};

// ---------------- software grid barrier (device/agent scope) ----------------
__device__ __forceinline__ void gbar(int* cnt, int* gen) {
    __syncthreads();
    if (threadIdx.x == 0) {
        __threadfence();    // release: prior writes visible device-wide
        int g = __hip_atomic_load(gen, __ATOMIC_RELAXED, __HIP_MEMORY_SCOPE_AGENT);
        int old = __hip_atomic_fetch_add(cnt, 1, __ATOMIC_ACQ_REL, __HIP_MEMORY_SCOPE_AGENT);
        if (old == (int)gridDim.x - 1) {
            // all arrived (stragglers only spin on gen) -> reset, then release
            __hip_atomic_store(cnt, 0, __ATOMIC_RELAXED, __HIP_MEMORY_SCOPE_AGENT);
            __hip_atomic_fetch_add(gen, 1, __ATOMIC_RELEASE, __HIP_MEMORY_SCOPE_AGENT);
        } else {
            while (__hip_atomic_load(gen, __ATOMIC_RELAXED, __HIP_MEMORY_SCOPE_AGENT) == g) {
                __builtin_amdgcn_s_sleep(1);
            }
        }
        __threadfence();    // acquire: other blocks' writes visible
    }
    __syncthreads();
}

// ---------------- numpy-pairwise combine (32 partials within a half-wave) ----------------
__device__ __forceinline__ float pairwise_combine(float r) {
    float o;
    o = __shfl_xor(r, 1, 64);  r = __fadd_rn(r, o);
    o = __shfl_xor(r, 2, 64);  r = __fadd_rn(r, o);
    o = __shfl_xor(r, 4, 64);  r = __fadd_rn(r, o);
    o = __shfl_xor(r, 8, 64);  r = __fadd_rn(r, o);
    o = __shfl_xor(r, 16, 64); r = __fadd_rn(r, o);
    return r;
}

// exact f32 emulation of sqrt((ax-bx)^2+(ay-by)^2) + |af-bf|
__device__ __forceinline__ float pair_dist_f32(float ax, float ay, float af,
                                               float bx, float by, float bf) {
    float dx = __fsub_rn(ax, bx);
    float dy = __fsub_rn(ay, by);
    float dx2 = __fmul_rn(dx, dx);
    float dy2 = __fmul_rn(dy, dy);
    float ss = __fadd_rn(dx2, dy2);
    float dxy = __fsqrt_rn(ss);
    float df = fabsf(__fsub_rn(af, bf));
    return __fadd_rn(dxy, df);
}

// inclusive scan of v across 512 threads (sm: 512 ints); returns inclusive value
__device__ __forceinline__ int block_incl_scan512(int v, int* sm) {
    sm[threadIdx.x] = v;
    __syncthreads();
    for (int off = 1; off < 512; off <<= 1) {
        int y = ((int)threadIdx.x >= off) ? sm[threadIdx.x - off] : 0;
        __syncthreads();
        sm[threadIdx.x] += y;
        __syncthreads();
    }
    return sm[threadIdx.x];   // own slot only; safe to overwrite next round
}

// =====================================================================
// Persistent mega-kernel. 240 blocks x 512 threads. 15 software barriers.
// Every phase is grid-strided over virtual chunks; no early block returns.
// =====================================================================
__global__ void __launch_bounds__(BLK_, 2) k_mega(MegaArgs a) {
    __shared__ float smem_f[PADC * 17];     // 9248 floats = 36992 B peak (fit)
    int* smem_i = (int*)smem_f;
    const int tid = threadIdx.x;
    const int bid = blockIdx.x;
    const int wv = tid >> 6, lane = tid & 63;

    // ---------- phase 0: {fit N1+N2} || {zero A, trivial outs, mintree, node0} ----------
    if ((bid & 7) != 3) {
        int fidx = bid - (bid >> 3) - (((bid & 7) > 3) ? 1 : 0);   // dense 0..209
        float* wbuf = smem_f;              // 544 floats, 4 groups of 136
        float* xbuf = smem_f + PADC;       // 16 rows x 544
        for (int g = fidx; g < NG16; g += FITB) {
            const float* w = (g < 512) ? a.w1 : a.w2;
            if (tid < 128) {
                float4 v = ((const float4*)w)[tid];
                ((float4*)wbuf)[((tid >> 5) * 34) + (tid & 31)] = v;
            }
            {
                int r0 = 2 * wv, r1 = r0 + 1;
                const float4* rA = (const float4*)(a.x + (size_t)(1 + 16 * g + r0) * C_);
                const float4* rB = (const float4*)(a.x + (size_t)(1 + 16 * g + r1) * C_);
                float4* xa = (float4*)(xbuf + (size_t)r0 * PADC);
                float4* xb = (float4*)(xbuf + (size_t)r1 * PADC);
                int j0 = lane, j1 = lane + 64;
                int d0 = ((j0 >> 5) * 34) + (j0 & 31);
                int d1 = ((j1 >> 5) * 34) + (j1 & 31);
                xa[d0] = rA[j0]; xa[d1] = rA[j1];
                xb[d0] = rB[j0]; xb[d1] = rB[j1];
            }
            __syncthreads();
            {
                int hl = lane & 31;
                int basep = ((hl >> 3) * 136) + (hl & 7);   // padded addr, same VALUES
                const float* xr = xbuf + (size_t)(2 * wv + (lane >> 5)) * PADC;
                float nv = wbuf[basep];
                float nr = __fmul_rn(nv, nv);
                float r = __fmul_rn(xr[basep], wbuf[basep]);
                #pragma unroll
                for (int i = 1; i < 16; ++i) {
                    int c = basep + 8 * i;
                    float u = wbuf[c];
                    nr = __fadd_rn(nr, __fmul_rn(u, u));
                    r = __fadd_rn(r, __fmul_rn(xr[c], u));
                }
                nr = pairwise_combine(nr);
                r = pairwise_combine(r);
                if (hl == 0) {
                    float nrm = __fsqrt_rn(nr);
                    float q = __fdiv_rn(r, nrm);
                    float f = (float)tanh((double)q);
                    int row16 = 16 * g + 2 * wv + (lane >> 5);
                    if (row16 < N1_) a.f1s[row16] = f;
                    else             a.f2s[row16 - N1_] = f;
                    a.out[OFF_FIT + 1 + row16] = f;
                }
            }
            __syncthreads();
        }
    } else {
        // zero role: 30 blocks, ztid in [0, 15360)
        int ztid = (bid >> 3) * BLK_ + tid;
        float* A = a.out + OFF_A;
        const long n4 = ((long)M_ * M_) >> 2;            // 4204550, tail = 1
        float4 z = make_float4(0.f, 0.f, 0.f, 0.f);
        for (long k4 = ztid; k4 < n4; k4 += ZTOT) ((float4*)A)[k4] = z;
        if (ztid == 0) {
            A[(size_t)n4 * 4] = 0.f;                     // last element
            a.clusterAll[0] = 0;
            a.out[OFF_CLUSTER] = 0.0f;
            a.out[OFF_FIT] = 0.0f;
        }
        if (ztid < M_) {
            a.out[OFF_NNT + ztid] = (ztid == 0) ? 0.0f : (ztid <= K1_ ? 1.0f : 2.0f);
            a.out[OFF_NTREE + ztid] = (ztid == 0) ? -1.0f
                                    : (ztid <= K1_ ? 0.0f : (float)(1 + (ztid - 1 - K1_) / 4));
            a.out[OFF_BATCH + ztid] = 0.0f;
        }
        int u = 0;                                       // max(INT_MAX - v)
        for (int i = ztid; i < N2_; i += ZTOT) {
            int v = a.tree[1 + N1_ + i];
            u = max(u, 0x7FFFFFFF - v);
        }
        for (int off = 32; off > 0; off >>= 1) u = max(u, __shfl_down(u, off, 64));
        if (lane == 0) atomicMax(a.minTreeNeg, u);
    }
    gbar(a.barCnt, a.barGen);

    // ---------- phase 1: rank of f1 (stable, f32 keys), 256 virtual tiles ----------
    for (int vb = bid; vb < 256; vb += G_) {
        float* buf = smem_f;
        int i = (vb >> 4) * 512 + tid;
        int jbase = (vb & 15) * 512;
        buf[tid] = a.f1s[jbase + tid];
        float fi = a.f1s[i];
        __syncthreads();
        int r = 0;
        #pragma unroll 8
        for (int j = 0; j < 512; ++j) {
            float fj = buf[j];
            int jj = jbase + j;
            r += (int)((fj < fi) || (fj == fi && jj < i));
        }
        atomicAdd(&a.rankArr[i], r);
        __syncthreads();
    }
    gbar(a.barCnt, a.barGen);

    // ---------- phase 2: decile thresholds -> (x,y,f) ----------
    for (int i = bid * BLK_ + tid; i < N1_; i += G_ * BLK_) {
        int r = a.rankArr[i];
        if (r % 10 == 0) {
            int k = r / 10;
            a.thrXYF[3 * k + 0] = a.xy[(size_t)(1 + i) * 2 + 0];
            a.thrXYF[3 * k + 1] = a.xy[(size_t)(1 + i) * 2 + 1];
            a.thrXYF[3 * k + 2] = a.f1s[i];
        }
    }
    gbar(a.barCnt, a.barGen);

    // ---------- phase 3: level-1 clustering ----------
    {
        float* t = smem_f;                               // 2460 floats
        for (int j = tid; j < K1_ * 3; j += BLK_) t[j] = a.thrXYF[j];
        __syncthreads();
        for (int gw = bid * 8 + wv; gw < N1_; gw += G_ * 8) {
            float xi = a.xy[(size_t)(1 + gw) * 2 + 0];
            float yi = a.xy[(size_t)(1 + gw) * 2 + 1];
            float fi = a.f1s[gw];
            float best = INFINITY; int bk = 0x7fffffff;
            for (int k = lane; k < K1_; k += 64) {
                float d = pair_dist_f32(t[3 * k + 0], t[3 * k + 1], t[3 * k + 2], xi, yi, fi);
                if (d < best || (d == best && k < bk)) { best = d; bk = k; }
            }
            for (int off = 32; off > 0; off >>= 1) {
                float ob = __shfl_down(best, off, 64);
                int ok = __shfl_down(bk, off, 64);
                if (ob < best || (ob == best && ok < bk)) { best = ob; bk = ok; }
            }
            if (lane == 0) {
                a.cluster1[gw] = bk;
                a.clusterAll[1 + gw] = bk + 1;
                a.out[OFF_CLUSTER + 1 + gw] = (float)(bk + 1);
            }
        }
    }
    gbar(a.barCnt, a.barGen);

    // ---------- phase 4: parents ----------
    {
        int mt = 0x7FFFFFFF - a.minTreeNeg[0];
        for (int i = bid * BLK_ + tid; i < N2_; i += G_ * BLK_) {
            a.parentsA[i] = a.cluster1[a.tree[1 + N1_ + i] - mt];
        }
    }
    gbar(a.barCnt, a.barGen);

    // ---------- phase 5: histP -> bcP[p][chunk] ----------
    for (int ch = bid; ch < NB2; ch += G_) {
        int* hist = smem_i;
        for (int j = tid; j < K1_; j += BLK_) hist[j] = 0;
        __syncthreads();
        int i = ch * 512 + tid;                          // N2 exact
        atomicAdd(&hist[a.parentsA[i]], 1);
        __syncthreads();
        for (int j = tid; j < K1_; j += BLK_) a.bcP[(size_t)j * NB2 + ch] = hist[j];
        __syncthreads();
    }
    gbar(a.barCnt, a.barGen);

    // ---------- phase 6: flat scan of bcP, part A (local chunk scans) ----------
    for (int ch = bid; ch < NCHS; ch += G_) {
        int base = ch * CHP;
        int e0 = 2 * tid, e1 = 2 * tid + 1;
        int v0 = (e0 < CHP) ? a.bcP[base + e0] : 0;
        int v1 = (e1 < CHP) ? a.bcP[base + e1] : 0;
        int s = v0 + v1;
        int incl = block_incl_scan512(s, smem_i);
        int excl = incl - s;
        if (e0 < CHP) a.bcP[base + e0] = excl;
        if (e1 < CHP) a.bcP[base + e1] = excl + v0;
        if (tid == 511) a.totP[ch] = incl;
        __syncthreads();
    }
    gbar(a.barCnt, a.barGen);

    // ---------- phase 7: scan chunk totals (block 0) ----------
    if (bid == 0) {
        int v = (tid < NCHS) ? a.totP[tid] : 0;
        int incl = block_incl_scan512(v, smem_i);
        if (tid < NCHS) a.coffP[tid] = incl - v;
    }
    gbar(a.barCnt, a.barGen);

    // ---------- phase 8: stable place parents -> plist ----------
    for (int ch = bid; ch < NB2; ch += G_) {
        int* par = smem_i;
        int i = ch * 512 + tid;
        int p = a.parentsA[i];
        par[tid] = p;
        __syncthreads();
        int rnk = 0;
        for (int j = 0; j < tid; ++j) rnk += (par[j] == p);
        int flat = p * NB2 + ch;
        a.plist[a.bcP[flat] + a.coffP[flat / CHP] + rnk] = i;
        __syncthreads();
    }
    gbar(a.barCnt, a.barGen);

    // ---------- phase 9: per-parent first-4 by (comp_key, index) ----------
    for (int p = bid * 8 + wv; p < K1_; p += G_ * 8) {
        int f0 = p * NB2;
        int f1 = (p + 1) * NB2;
        int lo = a.bcP[f0] + a.coffP[f0 / CHP];
        int hi = (p + 1 < K1_) ? (a.bcP[f1] + a.coffP[f1 / CHP]) : N2_;
        float basek = (float)(4 * p);
        float bk[4] = {INFINITY, INFINITY, INFINITY, INFINITY};
        int bi[4] = {-1, -1, -1, -1};
        for (int q = lo + lane; q < hi; q += 64) {
            int idx = a.plist[q];
            float key = __fadd_rn(basek, a.f2s[idx]);
            for (int j = 0; j < 4; ++j) {
                bool less = (key < bk[j]) || (key == bk[j] && (unsigned)idx < (unsigned)bi[j]);
                if (less) {
                    for (int r = 3; r > j; --r) { bk[r] = bk[r - 1]; bi[r] = bi[r - 1]; }
                    bk[j] = key; bi[j] = idx;
                    break;
                }
            }
        }
        for (int off = 1; off < 64; off <<= 1) {
            float ok_[4]; int oi[4];
            for (int j = 0; j < 4; ++j) {
                ok_[j] = __shfl_xor(bk[j], off, 64);
                oi[j]  = __shfl_xor(bi[j], off, 64);
            }
            float nk[4]; int ni[4];
            int ia = 0, ib2 = 0;
            for (int j = 0; j < 4; ++j) {
                bool takeA = (bk[ia] < ok_[ib2]) ||
                             (bk[ia] == ok_[ib2] && (unsigned)bi[ia] <= (unsigned)oi[ib2]);
                if (takeA) { nk[j] = bk[ia]; ni[j] = bi[ia]; ++ia; }
                else       { nk[j] = ok_[ib2]; ni[j] = oi[ib2]; ++ib2; }
            }
            for (int j = 0; j < 4; ++j) { bk[j] = nk[j]; bi[j] = ni[j]; }
        }
        if (lane == 0) {
            for (int j = 0; j < 4; ++j) a.cand[4 * p + j] = bi[j];
        }
    }
    gbar(a.barCnt, a.barGen);

    // ---------- phase 10: level-2 clustering ----------
    for (int i = bid * BLK_ + tid; i < N2_; i += G_ * BLK_) {
        int p = a.parentsA[i];
        float xi = a.xy[(size_t)(1 + N1_ + i) * 2 + 0];
        float yi = a.xy[(size_t)(1 + N1_ + i) * 2 + 1];
        float fi = a.f2s[i];
        float best = INFINITY; int bj = 0;
        for (int j = 0; j < 4; ++j) {
            int cidx = a.cand[4 * p + j];
            float d;
            if (cidx < 0) {
                d = INFINITY;
            } else {
                float ax = a.xy[(size_t)(1 + N1_ + cidx) * 2 + 0];
                float ay = a.xy[(size_t)(1 + N1_ + cidx) * 2 + 1];
                float af = a.f2s[cidx];
                d = pair_dist_f32(ax, ay, af, xi, yi, fi);
            }
            if (d < best) { best = d; bj = j; }
        }
        int c = p * 4 + bj + 1 + K1_;
        a.clusterAll[1 + N1_ + i] = c;
        a.out[OFF_CLUSTER + 1 + N1_ + i] = (float)c;
    }
    gbar(a.barCnt, a.barGen);

    // ---------- phase 11: histM -> bcM[c][chunk] ----------
    for (int ch = bid; ch < NBM; ch += G_) {
        int* hist = smem_i;                              // M_ ints = 16404 B
        for (int j = tid; j < M_; j += BLK_) hist[j] = 0;
        __syncthreads();
        int i = ch * 512 + tid;
        if (i < NTOT) atomicAdd(&hist[a.clusterAll[i]], 1);
        __syncthreads();
        for (int j = tid; j < M_; j += BLK_) a.bcM[(size_t)j * NBM + ch] = hist[j];
        __syncthreads();
    }
    gbar(a.barCnt, a.barGen);

    // ---------- phase 12: flat scan of bcM, part A ----------
    for (int ch = bid; ch < NCHS; ch += G_) {
        int base = ch * CHM;
        int ce = min(base + CHM, FLATM);
        int g0 = base + tid * 9;
        int v[9]; int s = 0;
        #pragma unroll
        for (int k = 0; k < 9; ++k) {
            int idx = g0 + k;
            v[k] = (idx < ce) ? a.bcM[idx] : 0;
            s += v[k];
        }
        int incl = block_incl_scan512(s, smem_i);
        int excl = incl - s;
        int run = excl;
        #pragma unroll
        for (int k = 0; k < 9; ++k) {
            int idx = g0 + k;
            if (idx < ce) { a.bcM[idx] = run; run += v[k]; }
        }
        if (tid == 511) a.totM[ch] = incl;
        __syncthreads();
    }
    gbar(a.barCnt, a.barGen);

    // ---------- phase 13: scan chunk totals (block 0) ----------
    if (bid == 0) {
        int v = (tid < NCHS) ? a.totM[tid] : 0;
        int incl = block_incl_scan512(v, smem_i);
        if (tid < NCHS) a.coffM[tid] = incl - v;
    }
    gbar(a.barCnt, a.barGen);

    // ---------- phase 14: stable place clusters -> clusterLst ----------
    for (int ch = bid; ch < NBM; ch += G_) {
        int* par = smem_i;
        int i = ch * 512 + tid;
        int c = (i < NTOT) ? a.clusterAll[i] : -1;
        par[tid] = c;
        __syncthreads();
        if (i < NTOT) {
            int rnk = 0;
            for (int j = 0; j < tid; ++j) rnk += (par[j] == c);
            int flat = c * NBM + ch;
            a.clusterLst[a.bcM[flat] + a.coffM[flat / CHM] + rnk] = i;
        }
        __syncthreads();
    }
    gbar(a.barCnt, a.barGen);

    // ---------- phase 15: edges (atomics) then pool (FROZEN f64 sequence) ----------
    {
        float* A = a.out + OFF_A;
        int gtid = bid * BLK_ + tid;
        for (long i = gtid; i < (long)E_ + NTOT; i += (long)G_ * BLK_) {
            if (i < E_) {
                int r = a.clusterAll[a.ei[i]];
                int c = a.clusterAll[a.ei[E_ + i]];
                atomicAdd(&A[(size_t)r * M_ + c], 1.0f);
            } else {
                int n = (int)(i - E_);
                int c = a.clusterAll[n];
                atomicAdd(&A[(size_t)c * M_ + c], 1.0f);
            }
        }
    }
    {
        int unit = bid * 4 + (tid >> 7);                 // 960 pool units of 128 thr
        int tsub = tid & 127;
        for (int m = unit; m < M_; m += G_ * 4) {
            int fl0 = m * NBM;
            int lo = a.bcM[fl0] + a.coffM[fl0 / CHM];
            int hi;
            if (m + 1 < M_) {
                int fl1 = (m + 1) * NBM;
                hi = a.bcM[fl1] + a.coffM[fl1 / CHM];
            } else hi = NTOT;
            double s0 = 0.0, s1 = 0.0, s2 = 0.0, s3 = 0.0, sx = 0.0, sy = 0.0;
            int q = lo;
            for (; q + 3 < hi; q += 4) {
                int n0 = a.clusterLst[q];
                int n1 = a.clusterLst[q + 1];
                int n2 = a.clusterLst[q + 2];
                int n3 = a.clusterLst[q + 3];
                float4 va = ((const float4*)(a.x + (size_t)n0 * C_))[tsub];
                float4 vb = ((const float4*)(a.x + (size_t)n1 * C_))[tsub];
                float4 vc = ((const float4*)(a.x + (size_t)n2 * C_))[tsub];
                float4 vd = ((const float4*)(a.x + (size_t)n3 * C_))[tsub];
                s0 += (double)va.x; s1 += (double)va.y; s2 += (double)va.z; s3 += (double)va.w;
                s0 += (double)vb.x; s1 += (double)vb.y; s2 += (double)vb.z; s3 += (double)vb.w;
                s0 += (double)vc.x; s1 += (double)vc.y; s2 += (double)vc.z; s3 += (double)vc.w;
                s0 += (double)vd.x; s1 += (double)vd.y; s2 += (double)vd.z; s3 += (double)vd.w;
                if (tsub == 0) {
                    sx += (double)a.xy[(size_t)n0 * 2 + 0] + (double)a.xy[(size_t)n1 * 2 + 0];
                    sx += (double)a.xy[(size_t)n2 * 2 + 0] + (double)a.xy[(size_t)n3 * 2 + 0];
                }
                if (tsub == 1) {
                    sy += (double)a.xy[(size_t)n0 * 2 + 1] + (double)a.xy[(size_t)n1 * 2 + 1];
                    sy += (double)a.xy[(size_t)n2 * 2 + 1] + (double)a.xy[(size_t)n3 * 2 + 1];
                }
            }
            for (; q + 1 < hi; q += 2) {
                int n0 = a.clusterLst[q];
                int n1 = a.clusterLst[q + 1];
                float4 va = ((const float4*)(a.x + (size_t)n0 * C_))[tsub];
                float4 vb = ((const float4*)(a.x + (size_t)n1 * C_))[tsub];
                s0 += (double)va.x; s1 += (double)va.y; s2 += (double)va.z; s3 += (double)va.w;
                s0 += (double)vb.x; s1 += (double)vb.y; s2 += (double)vb.z; s3 += (double)vb.w;
                if (tsub == 0) sx += (double)a.xy[(size_t)n0 * 2 + 0] + (double)a.xy[(size_t)n1 * 2 + 0];
                if (tsub == 1) sy += (double)a.xy[(size_t)n0 * 2 + 1] + (double)a.xy[(size_t)n1 * 2 + 1];
            }
            if (q < hi) {
                int n0 = a.clusterLst[q];
                float4 va = ((const float4*)(a.x + (size_t)n0 * C_))[tsub];
                s0 += (double)va.x; s1 += (double)va.y; s2 += (double)va.z; s3 += (double)va.w;
                if (tsub == 0) sx += (double)a.xy[(size_t)n0 * 2 + 0];
                if (tsub == 1) sy += (double)a.xy[(size_t)n0 * 2 + 1];
            }
            double cnt = (double)((hi - lo) > 0 ? (hi - lo) : 1);
            float4* xp = (float4*)(a.out + OFF_XPOOL + (size_t)m * C_);
            xp[tsub] = make_float4((float)(s0 / cnt), (float)(s1 / cnt),
                                   (float)(s2 / cnt), (float)(s3 / cnt));
            if (tsub == 0) a.out[OFF_NXY + 2 * (size_t)m + 0] = (float)(sx / cnt);
            if (tsub == 1) a.out[OFF_NXY + 2 * (size_t)m + 1] = (float)(sy / cnt);
        }
    }
}

extern "C" void kernel_launch(void* const* d_in, const int* in_sizes, int n_in,
                              void* d_out, int out_size, void* d_ws, size_t ws_size,
                              hipStream_t stream) {
    const float* x    = (const float*)d_in[0];
    const int*   ei   = (const int*)d_in[1];
    const int*   tree = (const int*)d_in[3];
    const float* xy   = (const float*)d_in[4];
    const float* w1   = (const float*)d_in[5];
    const float* w2   = (const float*)d_in[6];
    float* out = (float*)d_out;

    char* p = (char*)d_ws;
    auto alloc = [&](size_t nbytes) -> char* {
        char* r = p;
        p += (nbytes + 255) & ~(size_t)255;
        return r;
    };
    float*  f1s        = (float*)alloc((size_t)N1_ * 4);
    float*  f2s        = (float*)alloc((size_t)N2_ * 4);
    float*  thrXYF     = (float*)alloc((size_t)K1_ * 3 * 4);
    int*    cluster1   = (int*)alloc((size_t)N1_ * 4);
    int*    clusterAll = (int*)alloc((size_t)NTOT * 4);
    int*    parentsA   = (int*)alloc((size_t)N2_ * 4);
    int*    plist      = (int*)alloc((size_t)N2_ * 4);
    int*    clusterLst = (int*)alloc((size_t)NTOT * 4);
    int*    bcP        = (int*)alloc((size_t)FLATP * 4);
    int*    bcM        = (int*)alloc((size_t)FLATM * 4);
    int*    totP       = (int*)alloc(256 * 4);
    int*    coffP      = (int*)alloc(256 * 4);
    int*    totM       = (int*)alloc(256 * 4);
    int*    coffM      = (int*)alloc(256 * 4);
    // zero-initialized block: rankArr, minTreeNeg, barCnt, barGen
    size_t zeroInts = (size_t)N1_ + 3;
    char*   zeroBlk    = alloc(zeroInts * 4);
    int*    rankArr    = (int*)zeroBlk;
    int*    minTreeNeg = rankArr + N1_;
    int*    barCnt     = minTreeNeg + 1;
    int*    barGen     = barCnt + 1;
    int*    cand       = (int*)alloc((size_t)K1_ * 4 * 4);

    hipMemsetAsync(zeroBlk, 0, zeroInts * 4, stream);

    MegaArgs ha;
    ha.x = x; ha.ei = ei; ha.tree = tree; ha.xy = xy; ha.w1 = w1; ha.w2 = w2;
    ha.out = out;
    ha.f1s = f1s; ha.f2s = f2s; ha.thrXYF = thrXYF;
    ha.cluster1 = cluster1; ha.clusterAll = clusterAll; ha.parentsA = parentsA;
    ha.plist = plist; ha.clusterLst = clusterLst;
    ha.bcP = bcP; ha.bcM = bcM;
    ha.totP = totP; ha.coffP = coffP; ha.totM = totM; ha.coffM = coffM;
    ha.rankArr = rankArr; ha.minTreeNeg = minTreeNeg;
    ha.cand = cand;
    ha.barCnt = barCnt; ha.barGen = barGen;

    k_mega<<<G_, BLK_, 0, stream>>>(ha);
}

// Round 4
// 994.030 us; speedup vs baseline: 1.1485x; 1.1485x over previous
//
#include <hip/hip_runtime.h>
#include <cstdint>
#include <cstddef>
#include <math.h>

#define C_     512
#define N1_    8192
#define N2_    131072
#define NTOT   139265
#define E_     1000000
#define K1_    820
#define K2_    3280
#define M_     4101
#define NB2    256          // N2 / 512 histogram chunks
#define NBM    273          // ceil(NTOT / 512) histogram chunks
#define FLATP  209920       // K1_ * NB2
#define CHP    820          // FLATP / 256 scan chunks
#define FLATM  1119573      // M_ * NBM
#define CHM    4374         // ceil(FLATM / 256)
#define NCHS   256          // number of scan chunks (both P and M)

#define G_     240          // k_mid grid: < 256 CUs, ~16KB LDS -> co-residency safe
#define BLK_   512

#define FITBLKS 17408       // (N1_+N2_)/8 rows per block
#define ZBLKS   1024
#define ZTOT    262144      // ZBLKS*256

// d_out offsets (float elements), in reference return order
#define OFF_XPOOL   0ull
#define OFF_A       2099712ull
#define OFF_BATCH   18917913ull
#define OFF_CLUSTER 18922014ull
#define OFF_NNT     19061279ull
#define OFF_NTREE   19065380ull
#define OFF_FIT     19069481ull
#define OFF_NXY     19208746ull
#define OUT_TOTAL   19216948ull

// Discrete decisions emulate the reference's float32 arithmetic bit-exactly:
// numpy pairwise summation for dot products / norm, __f*_rn elementwise ops
// (no fma contraction), f32 keys, stable index tiebreaks. Bucket lists use a
// STABLE deterministic scatter (bit-identical output every call).
// FROZEN NUMERICS: per-row op sequence in fit, q-sequential f64 adds in
// pool — do not reorder. Fit LDS padding changes ADDRESSES only.
// HYBRID structure (round-4): streaming phases (fit/zero, pool/edges) are
// REGULAR full-occupancy launches (round-3 persistent version starved MLP:
// 605 GB/s, 20% occupancy); only the latency-bound mid-chain is persistent
// (240 blocks, 13 software grid barriers — barrier code validated round-3).

struct MidArgs {
    const int* tree; const float* xy;
    float* out;
    float* f1s; float* f2s; float* thrXYF;
    int* cluster1; int* clusterAll; int* parentsA; int* plist; int* clusterLst;
    int* bcP; int* bcM;
    int* totP; int* coffP; int* totM; int* coffM;
    int* rankArr; int* minTreeNeg;
    int* cand;
    int* barCnt; int* barGen;
};

// ---------------- software grid barrier (agent scope) — validated round-3 ----------------
__device__ __forceinline__ void gbar(int* cnt, int* gen) {
    __syncthreads();
    if (threadIdx.x == 0) {
        __threadfence();
        int g = __hip_atomic_load(gen, __ATOMIC_RELAXED, __HIP_MEMORY_SCOPE_AGENT);
        int old = __hip_atomic_fetch_add(cnt, 1, __ATOMIC_ACQ_REL, __HIP_MEMORY_SCOPE_AGENT);
        if (old == (int)gridDim.x - 1) {
            __hip_atomic_store(cnt, 0, __ATOMIC_RELAXED, __HIP_MEMORY_SCOPE_AGENT);
            __hip_atomic_fetch_add(gen, 1, __ATOMIC_RELEASE, __HIP_MEMORY_SCOPE_AGENT);
        } else {
            while (__hip_atomic_load(gen, __ATOMIC_RELAXED, __HIP_MEMORY_SCOPE_AGENT) == g) {
                __builtin_amdgcn_s_sleep(1);
            }
        }
        __threadfence();
    }
    __syncthreads();
}

// ---------------- numpy-pairwise combine (32 partials within a half-wave) ----------------
__device__ __forceinline__ float pairwise_combine(float r) {
    float o;
    o = __shfl_xor(r, 1, 64);  r = __fadd_rn(r, o);
    o = __shfl_xor(r, 2, 64);  r = __fadd_rn(r, o);
    o = __shfl_xor(r, 4, 64);  r = __fadd_rn(r, o);
    o = __shfl_xor(r, 8, 64);  r = __fadd_rn(r, o);
    o = __shfl_xor(r, 16, 64); r = __fadd_rn(r, o);
    return r;
}

// exact f32 emulation of sqrt((ax-bx)^2+(ay-by)^2) + |af-bf|
__device__ __forceinline__ float pair_dist_f32(float ax, float ay, float af,
                                               float bx, float by, float bf) {
    float dx = __fsub_rn(ax, bx);
    float dy = __fsub_rn(ay, by);
    float dx2 = __fmul_rn(dx, dx);
    float dy2 = __fmul_rn(dy, dy);
    float ss = __fadd_rn(dx2, dy2);
    float dxy = __fsqrt_rn(ss);
    float df = fabsf(__fsub_rn(af, bf));
    return __fadd_rn(dxy, df);
}

// inclusive scan of v across 512 threads (sm: 512 ints); returns inclusive value
__device__ __forceinline__ int block_incl_scan512(int v, int* sm) {
    sm[threadIdx.x] = v;
    __syncthreads();
    for (int off = 1; off < 512; off <<= 1) {
        int y = ((int)threadIdx.x >= off) ? sm[threadIdx.x - off] : 0;
        __syncthreads();
        sm[threadIdx.x] += y;
        __syncthreads();
    }
    return sm[threadIdx.x];
}

// =====================================================================
// k_front: fit (blocks [0,FITBLKS)) || zero-A + trivial outs + mintree.
// Fit: 4 waves/block, 2 rows/wave, padded LDS (bank-conflict-free),
// FROZEN per-row op sequence.
// =====================================================================
__global__ void __launch_bounds__(256) k_front(const float* __restrict__ x,
        const int* __restrict__ tree,
        const float* __restrict__ w1, const float* __restrict__ w2,
        float* __restrict__ out, float* __restrict__ f1s, float* __restrict__ f2s,
        int* __restrict__ clusterAll, int* __restrict__ minTreeNeg) {
    __shared__ float wbuf[544];
    __shared__ float xbuf[8][544];
    int bid = blockIdx.x, tid = threadIdx.x;
    int wv = tid >> 6, lane = tid & 63;
    if (bid < FITBLKS) {
        const float* w = (bid < 1024) ? w1 : w2;    // rows 1..8192 are type-1 (1024 blocks)
        if (tid < 128) {
            float4 v = ((const float4*)w)[tid];
            ((float4*)wbuf)[((tid >> 5) * 34) + (tid & 31)] = v;
        }
        int r0 = 2 * wv, r1 = r0 + 1;
        int rowA = 8 * bid + r0;
        const float4* rA = (const float4*)(x + (size_t)(1 + rowA) * C_);
        const float4* rB = (const float4*)(x + (size_t)(1 + rowA + 1) * C_);
        float4* xa = (float4*)xbuf[r0];
        float4* xb = (float4*)xbuf[r1];
        int j0 = lane, j1 = lane + 64;
        int d0 = ((j0 >> 5) * 34) + (j0 & 31);
        int d1 = ((j1 >> 5) * 34) + (j1 & 31);
        xa[d0] = rA[j0]; xa[d1] = rA[j1];
        xb[d0] = rB[j0]; xb[d1] = rB[j1];
        __syncthreads();
        int hl = lane & 31;
        int basep = ((hl >> 3) * 136) + (hl & 7);    // padded addr, same VALUES
        const float* xr = xbuf[2 * wv + (lane >> 5)];
        float nv = wbuf[basep];
        float nr = __fmul_rn(nv, nv);
        float r = __fmul_rn(xr[basep], wbuf[basep]);
        #pragma unroll
        for (int i = 1; i < 16; ++i) {
            int c = basep + 8 * i;
            float u = wbuf[c];
            nr = __fadd_rn(nr, __fmul_rn(u, u));
            r = __fadd_rn(r, __fmul_rn(xr[c], u));
        }
        nr = pairwise_combine(nr);
        r = pairwise_combine(r);
        if (hl == 0) {
            float nrm = __fsqrt_rn(nr);
            float q = __fdiv_rn(r, nrm);
            float f = (float)tanh((double)q);
            int rowIdx = 8 * bid + 2 * wv + (lane >> 5);
            if (rowIdx < N1_) f1s[rowIdx] = f;
            else              f2s[rowIdx - N1_] = f;
            out[OFF_FIT + 1 + rowIdx] = f;
        }
    } else {
        int ztid = (bid - FITBLKS) * 256 + tid;      // [0, 262144)
        float* A = out + OFF_A;
        const long n4 = ((long)M_ * M_) >> 2;        // 4204550, tail = 1
        float4 z = make_float4(0.f, 0.f, 0.f, 0.f);
        for (long k4 = ztid; k4 < n4; k4 += ZTOT) ((float4*)A)[k4] = z;
        if (ztid == 0) {
            A[(size_t)n4 * 4] = 0.f;
            clusterAll[0] = 0;
            out[OFF_CLUSTER] = 0.0f;
            out[OFF_FIT] = 0.0f;
        }
        if (ztid < M_) {
            out[OFF_NNT + ztid] = (ztid == 0) ? 0.0f : (ztid <= K1_ ? 1.0f : 2.0f);
            out[OFF_NTREE + ztid] = (ztid == 0) ? -1.0f
                                  : (ztid <= K1_ ? 0.0f : (float)(1 + (ztid - 1 - K1_) / 4));
            out[OFF_BATCH + ztid] = 0.0f;
        }
        int u = 0;                                   // max(INT_MAX - v)
        for (int i = ztid; i < N2_; i += ZTOT) {
            int v = tree[1 + N1_ + i];
            u = max(u, 0x7FFFFFFF - v);
        }
        for (int off = 32; off > 0; off >>= 1) u = max(u, __shfl_down(u, off, 64));
        if (lane == 0) atomicMax(minTreeNeg, u);
    }
}

// =====================================================================
// k_mid: persistent mid-chain, 240 blocks x 512 threads, 13 barriers.
// Phases copied from the PASSED round-3 kernel (phases 1..14).
// =====================================================================
__global__ void __launch_bounds__(BLK_, 2) k_mid(MidArgs a) {
    __shared__ int smem_i[M_];                        // 16404 B peak (histM)
    float* smem_f = (float*)smem_i;
    const int tid = threadIdx.x;
    const int bid = blockIdx.x;
    const int wv = tid >> 6, lane = tid & 63;

    // ---------- rank of f1 (stable, f32 keys), 256 virtual tiles ----------
    for (int vb = bid; vb < 256; vb += G_) {
        float* buf = smem_f;
        int i = (vb >> 4) * 512 + tid;
        int jbase = (vb & 15) * 512;
        buf[tid] = a.f1s[jbase + tid];
        float fi = a.f1s[i];
        __syncthreads();
        int r = 0;
        #pragma unroll 8
        for (int j = 0; j < 512; ++j) {
            float fj = buf[j];
            int jj = jbase + j;
            r += (int)((fj < fi) || (fj == fi && jj < i));
        }
        atomicAdd(&a.rankArr[i], r);
        __syncthreads();
    }
    gbar(a.barCnt, a.barGen);

    // ---------- decile thresholds -> (x,y,f) ----------
    for (int i = bid * BLK_ + tid; i < N1_; i += G_ * BLK_) {
        int r = a.rankArr[i];
        if (r % 10 == 0) {
            int k = r / 10;
            a.thrXYF[3 * k + 0] = a.xy[(size_t)(1 + i) * 2 + 0];
            a.thrXYF[3 * k + 1] = a.xy[(size_t)(1 + i) * 2 + 1];
            a.thrXYF[3 * k + 2] = a.f1s[i];
        }
    }
    gbar(a.barCnt, a.barGen);

    // ---------- level-1 clustering ----------
    {
        float* t = smem_f;                            // 2460 floats
        for (int j = tid; j < K1_ * 3; j += BLK_) t[j] = a.thrXYF[j];
        __syncthreads();
        for (int gw = bid * 8 + wv; gw < N1_; gw += G_ * 8) {
            float xi = a.xy[(size_t)(1 + gw) * 2 + 0];
            float yi = a.xy[(size_t)(1 + gw) * 2 + 1];
            float fi = a.f1s[gw];
            float best = INFINITY; int bk = 0x7fffffff;
            for (int k = lane; k < K1_; k += 64) {
                float d = pair_dist_f32(t[3 * k + 0], t[3 * k + 1], t[3 * k + 2], xi, yi, fi);
                if (d < best || (d == best && k < bk)) { best = d; bk = k; }
            }
            for (int off = 32; off > 0; off >>= 1) {
                float ob = __shfl_down(best, off, 64);
                int ok = __shfl_down(bk, off, 64);
                if (ob < best || (ob == best && ok < bk)) { best = ob; bk = ok; }
            }
            if (lane == 0) {
                a.cluster1[gw] = bk;
                a.clusterAll[1 + gw] = bk + 1;
                a.out[OFF_CLUSTER + 1 + gw] = (float)(bk + 1);
            }
        }
    }
    gbar(a.barCnt, a.barGen);

    // ---------- parents ----------
    {
        int mt = 0x7FFFFFFF - a.minTreeNeg[0];
        for (int i = bid * BLK_ + tid; i < N2_; i += G_ * BLK_) {
            a.parentsA[i] = a.cluster1[a.tree[1 + N1_ + i] - mt];
        }
    }
    gbar(a.barCnt, a.barGen);

    // ---------- histP -> bcP[p][chunk] ----------
    for (int ch = bid; ch < NB2; ch += G_) {
        int* hist = smem_i;
        for (int j = tid; j < K1_; j += BLK_) hist[j] = 0;
        __syncthreads();
        int i = ch * 512 + tid;                       // N2 exact
        atomicAdd(&hist[a.parentsA[i]], 1);
        __syncthreads();
        for (int j = tid; j < K1_; j += BLK_) a.bcP[(size_t)j * NB2 + ch] = hist[j];
        __syncthreads();
    }
    gbar(a.barCnt, a.barGen);

    // ---------- flat scan of bcP: local chunk scans ----------
    for (int ch = bid; ch < NCHS; ch += G_) {
        int base = ch * CHP;
        int e0 = 2 * tid, e1 = 2 * tid + 1;
        int v0 = (e0 < CHP) ? a.bcP[base + e0] : 0;
        int v1 = (e1 < CHP) ? a.bcP[base + e1] : 0;
        int s = v0 + v1;
        int incl = block_incl_scan512(s, smem_i);
        int excl = incl - s;
        if (e0 < CHP) a.bcP[base + e0] = excl;
        if (e1 < CHP) a.bcP[base + e1] = excl + v0;
        if (tid == 511) a.totP[ch] = incl;
        __syncthreads();
    }
    gbar(a.barCnt, a.barGen);

    // ---------- scan chunk totals (block 0) ----------
    if (bid == 0) {
        int v = (tid < NCHS) ? a.totP[tid] : 0;
        int incl = block_incl_scan512(v, smem_i);
        if (tid < NCHS) a.coffP[tid] = incl - v;
    }
    gbar(a.barCnt, a.barGen);

    // ---------- stable place parents -> plist ----------
    for (int ch = bid; ch < NB2; ch += G_) {
        int* par = smem_i;
        int i = ch * 512 + tid;
        int p = a.parentsA[i];
        par[tid] = p;
        __syncthreads();
        int rnk = 0;
        for (int j = 0; j < tid; ++j) rnk += (par[j] == p);
        int flat = p * NB2 + ch;
        a.plist[a.bcP[flat] + a.coffP[flat / CHP] + rnk] = i;
        __syncthreads();
    }
    gbar(a.barCnt, a.barGen);

    // ---------- per-parent first-4 by (comp_key, index) ----------
    for (int p = bid * 8 + wv; p < K1_; p += G_ * 8) {
        int f0 = p * NB2;
        int f1 = (p + 1) * NB2;
        int lo = a.bcP[f0] + a.coffP[f0 / CHP];
        int hi = (p + 1 < K1_) ? (a.bcP[f1] + a.coffP[f1 / CHP]) : N2_;
        float basek = (float)(4 * p);
        float bk[4] = {INFINITY, INFINITY, INFINITY, INFINITY};
        int bi[4] = {-1, -1, -1, -1};
        for (int q = lo + lane; q < hi; q += 64) {
            int idx = a.plist[q];
            float key = __fadd_rn(basek, a.f2s[idx]);
            for (int j = 0; j < 4; ++j) {
                bool less = (key < bk[j]) || (key == bk[j] && (unsigned)idx < (unsigned)bi[j]);
                if (less) {
                    for (int r = 3; r > j; --r) { bk[r] = bk[r - 1]; bi[r] = bi[r - 1]; }
                    bk[j] = key; bi[j] = idx;
                    break;
                }
            }
        }
        for (int off = 1; off < 64; off <<= 1) {
            float ok_[4]; int oi[4];
            for (int j = 0; j < 4; ++j) {
                ok_[j] = __shfl_xor(bk[j], off, 64);
                oi[j]  = __shfl_xor(bi[j], off, 64);
            }
            float nk[4]; int ni[4];
            int ia = 0, ib2 = 0;
            for (int j = 0; j < 4; ++j) {
                bool takeA = (bk[ia] < ok_[ib2]) ||
                             (bk[ia] == ok_[ib2] && (unsigned)bi[ia] <= (unsigned)oi[ib2]);
                if (takeA) { nk[j] = bk[ia]; ni[j] = bi[ia]; ++ia; }
                else       { nk[j] = ok_[ib2]; ni[j] = oi[ib2]; ++ib2; }
            }
            for (int j = 0; j < 4; ++j) { bk[j] = nk[j]; bi[j] = ni[j]; }
        }
        if (lane == 0) {
            for (int j = 0; j < 4; ++j) a.cand[4 * p + j] = bi[j];
        }
    }
    gbar(a.barCnt, a.barGen);

    // ---------- level-2 clustering ----------
    for (int i = bid * BLK_ + tid; i < N2_; i += G_ * BLK_) {
        int p = a.parentsA[i];
        float xi = a.xy[(size_t)(1 + N1_ + i) * 2 + 0];
        float yi = a.xy[(size_t)(1 + N1_ + i) * 2 + 1];
        float fi = a.f2s[i];
        float best = INFINITY; int bj = 0;
        for (int j = 0; j < 4; ++j) {
            int cidx = a.cand[4 * p + j];
            float d;
            if (cidx < 0) {
                d = INFINITY;
            } else {
                float ax = a.xy[(size_t)(1 + N1_ + cidx) * 2 + 0];
                float ay = a.xy[(size_t)(1 + N1_ + cidx) * 2 + 1];
                float af = a.f2s[cidx];
                d = pair_dist_f32(ax, ay, af, xi, yi, fi);
            }
            if (d < best) { best = d; bj = j; }
        }
        int c = p * 4 + bj + 1 + K1_;
        a.clusterAll[1 + N1_ + i] = c;
        a.out[OFF_CLUSTER + 1 + N1_ + i] = (float)c;
    }
    gbar(a.barCnt, a.barGen);

    // ---------- histM -> bcM[c][chunk] ----------
    for (int ch = bid; ch < NBM; ch += G_) {
        int* hist = smem_i;                           // M_ ints
        for (int j = tid; j < M_; j += BLK_) hist[j] = 0;
        __syncthreads();
        int i = ch * 512 + tid;
        if (i < NTOT) atomicAdd(&hist[a.clusterAll[i]], 1);
        __syncthreads();
        for (int j = tid; j < M_; j += BLK_) a.bcM[(size_t)j * NBM + ch] = hist[j];
        __syncthreads();
    }
    gbar(a.barCnt, a.barGen);

    // ---------- flat scan of bcM: local chunk scans ----------
    for (int ch = bid; ch < NCHS; ch += G_) {
        int base = ch * CHM;
        int ce = min(base + CHM, FLATM);
        int g0 = base + tid * 9;
        int v[9]; int s = 0;
        #pragma unroll
        for (int k = 0; k < 9; ++k) {
            int idx = g0 + k;
            v[k] = (idx < ce) ? a.bcM[idx] : 0;
            s += v[k];
        }
        int incl = block_incl_scan512(s, smem_i);
        int excl = incl - s;
        int run = excl;
        #pragma unroll
        for (int k = 0; k < 9; ++k) {
            int idx = g0 + k;
            if (idx < ce) { a.bcM[idx] = run; run += v[k]; }
        }
        if (tid == 511) a.totM[ch] = incl;
        __syncthreads();
    }
    gbar(a.barCnt, a.barGen);

    // ---------- scan chunk totals (block 0) ----------
    if (bid == 0) {
        int v = (tid < NCHS) ? a.totM[tid] : 0;
        int incl = block_incl_scan512(v, smem_i);
        if (tid < NCHS) a.coffM[tid] = incl - v;
    }
    gbar(a.barCnt, a.barGen);

    // ---------- stable place clusters -> clusterLst ----------
    for (int ch = bid; ch < NBM; ch += G_) {
        int* par = smem_i;
        int i = ch * 512 + tid;
        int c = (i < NTOT) ? a.clusterAll[i] : -1;
        par[tid] = c;
        __syncthreads();
        if (i < NTOT) {
            int rnk = 0;
            for (int j = 0; j < tid; ++j) rnk += (par[j] == c);
            int flat = c * NBM + ch;
            a.clusterLst[a.bcM[flat] + a.coffM[flat / CHM] + rnk] = i;
        }
        __syncthreads();
    }
}

// =====================================================================
// k_tail: pool (blocks [0,M_), FROZEN f64 q-order sequence) + edges.
// lo/hi derived from the flat bcM/coffM two-level scan.
// =====================================================================
__global__ void __launch_bounds__(128) k_tail(const float* __restrict__ x,
        const float* __restrict__ xy,
        const int* __restrict__ bcM, const int* __restrict__ coffM,
        const int* __restrict__ clusterList,
        const int* __restrict__ ei, const int* __restrict__ clusterAll,
        float* __restrict__ out) {
    int bid = blockIdx.x;
    if (bid < M_) {
        int m = bid;
        int fl0 = m * NBM;
        int lo = bcM[fl0] + coffM[fl0 / CHM];
        int hi;
        if (m + 1 < M_) {
            int fl1 = (m + 1) * NBM;
            hi = bcM[fl1] + coffM[fl1 / CHM];
        } else hi = NTOT;
        int t = threadIdx.x;   // 0..127, channels 4t..4t+3
        double s0 = 0.0, s1 = 0.0, s2 = 0.0, s3 = 0.0, sx = 0.0, sy = 0.0;
        int q = lo;
        for (; q + 3 < hi; q += 4) {
            int n0 = clusterList[q];
            int n1 = clusterList[q + 1];
            int n2 = clusterList[q + 2];
            int n3 = clusterList[q + 3];
            float4 va = ((const float4*)(x + (size_t)n0 * C_))[t];
            float4 vb = ((const float4*)(x + (size_t)n1 * C_))[t];
            float4 vc = ((const float4*)(x + (size_t)n2 * C_))[t];
            float4 vd = ((const float4*)(x + (size_t)n3 * C_))[t];
            s0 += (double)va.x; s1 += (double)va.y; s2 += (double)va.z; s3 += (double)va.w;
            s0 += (double)vb.x; s1 += (double)vb.y; s2 += (double)vb.z; s3 += (double)vb.w;
            s0 += (double)vc.x; s1 += (double)vc.y; s2 += (double)vc.z; s3 += (double)vc.w;
            s0 += (double)vd.x; s1 += (double)vd.y; s2 += (double)vd.z; s3 += (double)vd.w;
            if (t == 0) {
                sx += (double)xy[(size_t)n0 * 2 + 0] + (double)xy[(size_t)n1 * 2 + 0];
                sx += (double)xy[(size_t)n2 * 2 + 0] + (double)xy[(size_t)n3 * 2 + 0];
            }
            if (t == 1) {
                sy += (double)xy[(size_t)n0 * 2 + 1] + (double)xy[(size_t)n1 * 2 + 1];
                sy += (double)xy[(size_t)n2 * 2 + 1] + (double)xy[(size_t)n3 * 2 + 1];
            }
        }
        for (; q + 1 < hi; q += 2) {
            int n0 = clusterList[q];
            int n1 = clusterList[q + 1];
            float4 va = ((const float4*)(x + (size_t)n0 * C_))[t];
            float4 vb = ((const float4*)(x + (size_t)n1 * C_))[t];
            s0 += (double)va.x; s1 += (double)va.y; s2 += (double)va.z; s3 += (double)va.w;
            s0 += (double)vb.x; s1 += (double)vb.y; s2 += (double)vb.z; s3 += (double)vb.w;
            if (t == 0) sx += (double)xy[(size_t)n0 * 2 + 0] + (double)xy[(size_t)n1 * 2 + 0];
            if (t == 1) sy += (double)xy[(size_t)n0 * 2 + 1] + (double)xy[(size_t)n1 * 2 + 1];
        }
        if (q < hi) {
            int n0 = clusterList[q];
            float4 va = ((const float4*)(x + (size_t)n0 * C_))[t];
            s0 += (double)va.x; s1 += (double)va.y; s2 += (double)va.z; s3 += (double)va.w;
            if (t == 0) sx += (double)xy[(size_t)n0 * 2 + 0];
            if (t == 1) sy += (double)xy[(size_t)n0 * 2 + 1];
        }
        double cnt = (double)((hi - lo) > 0 ? (hi - lo) : 1);
        float4* xp = (float4*)(out + OFF_XPOOL + (size_t)m * C_);
        xp[t] = make_float4((float)(s0 / cnt), (float)(s1 / cnt),
                            (float)(s2 / cnt), (float)(s3 / cnt));
        if (t == 0) out[OFF_NXY + 2 * (size_t)m + 0] = (float)(sx / cnt);
        if (t == 1) out[OFF_NXY + 2 * (size_t)m + 1] = (float)(sy / cnt);
    } else {
        int i = (bid - M_) * 128 + threadIdx.x;
        float* A = out + OFF_A;
        if (i < E_) {
            int r = clusterAll[ei[i]];
            int c = clusterAll[ei[E_ + i]];
            atomicAdd(&A[(size_t)r * M_ + c], 1.0f);
        } else {
            int n = i - E_;
            if (n < NTOT) {
                int c = clusterAll[n];
                atomicAdd(&A[(size_t)c * M_ + c], 1.0f);
            }
        }
    }
}

extern "C" void kernel_launch(void* const* d_in, const int* in_sizes, int n_in,
                              void* d_out, int out_size, void* d_ws, size_t ws_size,
                              hipStream_t stream) {
    const float* x    = (const float*)d_in[0];
    const int*   ei   = (const int*)d_in[1];
    const int*   tree = (const int*)d_in[3];
    const float* xy   = (const float*)d_in[4];
    const float* w1   = (const float*)d_in[5];
    const float* w2   = (const float*)d_in[6];
    float* out = (float*)d_out;

    char* p = (char*)d_ws;
    auto alloc = [&](size_t nbytes) -> char* {
        char* r = p;
        p += (nbytes + 255) & ~(size_t)255;
        return r;
    };
    float*  f1s        = (float*)alloc((size_t)N1_ * 4);
    float*  f2s        = (float*)alloc((size_t)N2_ * 4);
    float*  thrXYF     = (float*)alloc((size_t)K1_ * 3 * 4);
    int*    cluster1   = (int*)alloc((size_t)N1_ * 4);
    int*    clusterAll = (int*)alloc((size_t)NTOT * 4);
    int*    parentsA   = (int*)alloc((size_t)N2_ * 4);
    int*    plist      = (int*)alloc((size_t)N2_ * 4);
    int*    clusterLst = (int*)alloc((size_t)NTOT * 4);
    int*    bcP        = (int*)alloc((size_t)FLATP * 4);
    int*    bcM        = (int*)alloc((size_t)FLATM * 4);
    int*    totP       = (int*)alloc(256 * 4);
    int*    coffP      = (int*)alloc(256 * 4);
    int*    totM       = (int*)alloc(256 * 4);
    int*    coffM      = (int*)alloc(256 * 4);
    // zero-initialized block: rankArr, minTreeNeg, barCnt, barGen
    size_t zeroInts = (size_t)N1_ + 3;
    char*   zeroBlk    = alloc(zeroInts * 4);
    int*    rankArr    = (int*)zeroBlk;
    int*    minTreeNeg = rankArr + N1_;
    int*    barCnt     = minTreeNeg + 1;
    int*    barGen     = barCnt + 1;
    int*    cand       = (int*)alloc((size_t)K1_ * 4 * 4);

    hipMemsetAsync(zeroBlk, 0, zeroInts * 4, stream);

    k_front<<<FITBLKS + ZBLKS, 256, 0, stream>>>(x, tree, w1, w2, out,
                                                 f1s, f2s, clusterAll, minTreeNeg);

    MidArgs ha;
    ha.tree = tree; ha.xy = xy; ha.out = out;
    ha.f1s = f1s; ha.f2s = f2s; ha.thrXYF = thrXYF;
    ha.cluster1 = cluster1; ha.clusterAll = clusterAll; ha.parentsA = parentsA;
    ha.plist = plist; ha.clusterLst = clusterLst;
    ha.bcP = bcP; ha.bcM = bcM;
    ha.totP = totP; ha.coffP = coffP; ha.totM = totM; ha.coffM = coffM;
    ha.rankArr = rankArr; ha.minTreeNeg = minTreeNeg;
    ha.cand = cand;
    ha.barCnt = barCnt; ha.barGen = barGen;
    k_mid<<<G_, BLK_, 0, stream>>>(ha);

    k_tail<<<M_ + (E_ + NTOT + 127) / 128, 128, 0, stream>>>(
        x, xy, bcM, coffM, clusterLst, ei, clusterAll, out);
}